// Round 5
// baseline (20.521 us; speedup 1.0000x reference)
//
#include <hip/hip_runtime.h>
#include <math.h>

// ---- problem constants ----
#define NB    512   // batch
#define STATE 512
#define IMS   224
#define TSB   768   // 3*16*16
#define HGN   128
#define GN    256
#define WPITCH 65   // 64 + 1 pad
#define SPB   4     // samples per block

// ---- static LDS layout (aliased regions; total 83072 B) ----
// [0, 66560)        : win[4][64*WPITCH] f32       (phases 2-3)
//   [0, 32768)      : part4[4][16][128] f32       (phases 4-5, aliases win)
//   [32768, 65536)  : part6[4][8][256]  f32       (phase 6, aliases win)
// [66560, 78848)    : gl[4][768] f32
// [78848, 80896)    : s_hg[4][128] f32
// [80896, 82944)    : s_hl[4][128] f32
// [82944, 83008)    : red[8][2] f32
// [83008, 83040)    : s_loc[4][2] f32
// [83040, 83072)    : s_li[4][2] int
#define SM_WIN   0
#define SM_P4    0
#define SM_P6    32768
#define SM_GL    66560
#define SM_HG    78848
#define SM_HL    80896
#define SM_RED   82944
#define SM_LOC   83008
#define SM_LI    83040
#define SM_TOTAL 83072

// depth-1 (32->16) antialiased linear weights: taps at j = 2*o-1 + a
__device__ __forceinline__ void d1w(int o, float w[4]) {
    w[0] = 0.125f; w[1] = 0.375f; w[2] = 0.375f; w[3] = 0.125f;
    if (o == 0)  { w[0] = 0.f;      w[1] = 3.f/7.f; w[2] = 3.f/7.f; w[3] = 1.f/7.f; }
    if (o == 15) { w[0] = 1.f/7.f;  w[1] = 3.f/7.f; w[2] = 3.f/7.f; w[3] = 0.f; }
}
// depth-2 (64->16) weights: taps at j = 4*o-2 + a
__device__ __forceinline__ void d2w(int o, float w[8]) {
    const float s = 1.f/32.f;
    w[0]=1*s; w[1]=3*s; w[2]=5*s; w[3]=7*s; w[4]=7*s; w[5]=5*s; w[6]=3*s; w[7]=1*s;
    if (o == 0)  { const float t=1.f/28.f; w[0]=0.f; w[1]=0.f; w[2]=5*t; w[3]=7*t; w[4]=7*t; w[5]=5*t; w[6]=3*t; w[7]=1*t; }
    if (o == 15) { const float t=1.f/28.f; w[0]=1*t; w[1]=3*t; w[2]=5*t; w[3]=7*t; w[4]=7*t; w[5]=5*t; w[6]=0.f; w[7]=0.f; }
}

// Fully fused: loc -> glimpses -> hg -> hl -> g.  4 samples per block, 512 thr.
// Weight loads in the GEMV phases are shared across the block's 4 samples.
__global__ __launch_bounds__(512) void fused_attn(
    const float* __restrict__ out_state,  // [512][512]
    const float* __restrict__ img,        // [512][224][224]
    const float* __restrict__ W_loc, const float* __restrict__ b_loc,
    const float* __restrict__ W_hg,  const float* __restrict__ b_hg,
    const float* __restrict__ W_hl,  const float* __restrict__ b_hl,
    const float* __restrict__ W_gs,  const float* __restrict__ b_gs,
    const float* __restrict__ W_ls,  const float* __restrict__ b_ls,
    float* __restrict__ out)              // [512][256]
{
    __shared__ __align__(16) char smem[SM_TOTAL];
    float* win   = (float*)(smem + SM_WIN);    // [4][64*WPITCH]
    float* part4 = (float*)(smem + SM_P4);     // [4][16][128]
    float* part6 = (float*)(smem + SM_P6);     // [4][8][256]
    float* gl    = (float*)(smem + SM_GL);     // [4][768]
    float* s_hg  = (float*)(smem + SM_HG);     // [4][128]
    float* s_hl  = (float*)(smem + SM_HL);     // [4][128]
    float* red   = (float*)(smem + SM_RED);    // [8][2]
    float* s_loc = (float*)(smem + SM_LOC);    // [4][2]
    int*   s_li  = (int*)(smem + SM_LI);       // [4][2]

    const int t  = threadIdx.x;
    const int b0 = blockIdx.x * SPB;

    // ---- phase 1: loc = clip(output @ W_loc + b_loc); 128 threads/sample
    {
        int s = t >> 7, k = t & 127;
        const float* orow = out_state + (size_t)(b0 + s) * STATE;
        float a0 = 0.f, a1 = 0.f;
        #pragma unroll
        for (int i = 0; i < 4; ++i) {
            float x = orow[k + i * 128];
            a0 += x * W_loc[(k + i*128) * 2];
            a1 += x * W_loc[(k + i*128) * 2 + 1];
        }
        for (int off = 32; off; off >>= 1) {
            a0 += __shfl_down(a0, off);
            a1 += __shfl_down(a1, off);
        }
        if ((t & 63) == 0) { red[(t>>6)*2] = a0; red[(t>>6)*2 + 1] = a1; }
    }
    __syncthreads();
    if ((t & 127) == 0) {
        int s = t >> 7;   // waves 2s, 2s+1 hold this sample's partials
        float l0 = red[4*s]     + red[4*s + 2] + b_loc[0];
        float l1 = red[4*s + 1] + red[4*s + 3] + b_loc[1];
        l0 = fminf(fmaxf(l0, -1.f), 1.f);
        l1 = fminf(fmaxf(l1, -1.f), 1.f);
        s_loc[s*2] = l0; s_loc[s*2 + 1] = l1;
        s_li[s*2]     = (int)rintf((l0 + 1.f) * 0.5f * (float)IMS);
        s_li[s*2 + 1] = (int)rintf((l1 + 1.f) * 0.5f * (float)IMS);
    }
    __syncthreads();

    // ---- phase 2: 64x64 windows centered at loc, zero outside image
    #pragma unroll
    for (int i = 0; i < 32; ++i) {
        int idx = t + i * 512;
        int s = idx >> 12, rem = idx & 4095;
        int r = rem >> 6, c = rem & 63;
        int rr = s_li[s*2] - 32 + r, cc = s_li[s*2 + 1] - 32 + c;
        float v = 0.f;
        if ((unsigned)rr < (unsigned)IMS && (unsigned)cc < (unsigned)IMS)
            v = img[(size_t)(b0 + s) * IMS * IMS + rr * IMS + cc];
        win[s * (64*WPITCH) + r * WPITCH + c] = v;
    }
    __syncthreads();

    // ---- phase 3: 3-depth glimpses -> gl LDS (1024 work items, 2 per thread)
    #pragma unroll
    for (int ii = 0; ii < 2; ++ii) {
        int idx = t + ii * 512;
        int s = idx >> 8, p = idx & 255, r = p >> 4, c = p & 15;
        const float* w = win + s * (64*WPITCH);
        float* glp = gl + s * TSB;
        glp[p] = w[(24 + r) * WPITCH + (24 + c)];
        {
            float wr[4], wc[4];
            d1w(r, wr); d1w(c, wc);
            int jr0 = 16 + 2*r - 1, jc0 = 16 + 2*c - 1;
            float acc = 0.f;
            #pragma unroll
            for (int a = 0; a < 4; ++a) {
                float rowsum = 0.f;
                #pragma unroll
                for (int bb = 0; bb < 4; ++bb)
                    rowsum += wc[bb] * w[(jr0 + a) * WPITCH + (jc0 + bb)];
                acc += wr[a] * rowsum;
            }
            glp[256 + p] = acc;
        }
        {
            float wr[8], wc[8];
            d2w(r, wr); d2w(c, wc);
            int jr0 = 4*r - 2, jc0 = 4*c - 2;
            float acc = 0.f;
            #pragma unroll
            for (int a = 0; a < 8; ++a) {
                int jr = min(max(jr0 + a, 0), 63);
                float rowsum = 0.f;
                #pragma unroll
                for (int bb = 0; bb < 8; ++bb) {
                    int jc = min(max(jc0 + bb, 0), 63);
                    rowsum += wc[bb] * w[jr * WPITCH + jc];
                }
                acc += wr[a] * rowsum;
            }
            glp[512 + p] = acc;
        }
    }
    __syncthreads();

    // ---- phase 4: hg partials, weights shared across 4 samples
    // thread: cg = t&31 (4 cols), q = t>>5 (0..15, 48 k each)
    {
        int cg = t & 31, q = t >> 5;
        const float* g0 = gl + 0*TSB + q * 48;
        const float* g1 = gl + 1*TSB + q * 48;
        const float* g2 = gl + 2*TSB + q * 48;
        const float* g3 = gl + 3*TSB + q * 48;
        const float* wp = W_hg + (size_t)(q * 48) * HGN + cg * 4;
        float4 acc0 = make_float4(0.f,0.f,0.f,0.f);
        float4 acc1 = acc0, acc2 = acc0, acc3 = acc0;
        #pragma unroll 8
        for (int k = 0; k < 48; ++k) {
            float4 w4 = *(const float4*)(wp + (size_t)k * HGN);
            float a = g0[k], b = g1[k], c = g2[k], d = g3[k];
            acc0.x += a*w4.x; acc0.y += a*w4.y; acc0.z += a*w4.z; acc0.w += a*w4.w;
            acc1.x += b*w4.x; acc1.y += b*w4.y; acc1.z += b*w4.z; acc1.w += b*w4.w;
            acc2.x += c*w4.x; acc2.y += c*w4.y; acc2.z += c*w4.z; acc2.w += c*w4.w;
            acc3.x += d*w4.x; acc3.y += d*w4.y; acc3.z += d*w4.z; acc3.w += d*w4.w;
        }
        *(float4*)&part4[(0*16 + q)*HGN + cg*4] = acc0;
        *(float4*)&part4[(1*16 + q)*HGN + cg*4] = acc1;
        *(float4*)&part4[(2*16 + q)*HGN + cg*4] = acc2;
        *(float4*)&part4[(3*16 + q)*HGN + cg*4] = acc3;
    }
    __syncthreads();

    // ---- phase 5: reduce hg partials + compute hl (one output per thread)
    {
        int s = t >> 7, col = t & 127;
        float a = b_hg[col];
        #pragma unroll
        for (int q = 0; q < 16; ++q) a += part4[(s*16 + q)*HGN + col];
        s_hg[s*HGN + col] = fmaxf(a, 0.f);
        float l0 = s_loc[s*2], l1 = s_loc[s*2 + 1];
        s_hl[s*HGN + col] = fmaxf(l0 * W_hl[col] + l1 * W_hl[HGN + col] + b_hl[col], 0.f);
    }
    __syncthreads();

    // ---- phase 6: g partials, weights shared across 4 samples
    // thread: cg = t&63 (4 cols of 256), q = t>>6 (0..7, 16 j each)
    {
        int cg = t & 63, q = t >> 6;
        const float* wgs = W_gs + (size_t)(q * 16) * GN + cg * 4;
        const float* wls = W_ls + (size_t)(q * 16) * GN + cg * 4;
        float4 acc0 = make_float4(0.f,0.f,0.f,0.f);
        float4 acc1 = acc0, acc2 = acc0, acc3 = acc0;
        #pragma unroll 4
        for (int j = 0; j < 16; ++j) {
            float4 a4 = *(const float4*)(wgs + (size_t)j * GN);
            float4 b4 = *(const float4*)(wls + (size_t)j * GN);
            int jj = q * 16 + j;
            float hg0 = s_hg[0*HGN + jj], hl0 = s_hl[0*HGN + jj];
            float hg1 = s_hg[1*HGN + jj], hl1 = s_hl[1*HGN + jj];
            float hg2 = s_hg[2*HGN + jj], hl2 = s_hl[2*HGN + jj];
            float hg3 = s_hg[3*HGN + jj], hl3 = s_hl[3*HGN + jj];
            acc0.x += hg0*a4.x + hl0*b4.x; acc0.y += hg0*a4.y + hl0*b4.y;
            acc0.z += hg0*a4.z + hl0*b4.z; acc0.w += hg0*a4.w + hl0*b4.w;
            acc1.x += hg1*a4.x + hl1*b4.x; acc1.y += hg1*a4.y + hl1*b4.y;
            acc1.z += hg1*a4.z + hl1*b4.z; acc1.w += hg1*a4.w + hl1*b4.w;
            acc2.x += hg2*a4.x + hl2*b4.x; acc2.y += hg2*a4.y + hl2*b4.y;
            acc2.z += hg2*a4.z + hl2*b4.z; acc2.w += hg2*a4.w + hl2*b4.w;
            acc3.x += hg3*a4.x + hl3*b4.x; acc3.y += hg3*a4.y + hl3*b4.y;
            acc3.z += hg3*a4.z + hl3*b4.z; acc3.w += hg3*a4.w + hl3*b4.w;
        }
        *(float4*)&part6[(0*8 + q)*GN + cg*4] = acc0;
        *(float4*)&part6[(1*8 + q)*GN + cg*4] = acc1;
        *(float4*)&part6[(2*8 + q)*GN + cg*4] = acc2;
        *(float4*)&part6[(3*8 + q)*GN + cg*4] = acc3;
    }
    __syncthreads();
    // ---- final reduce: 1024 outputs, 2 per thread
    {
        int n = t & 255, s0 = t >> 8;   // s0 in {0,1} -> samples s0, s0+2
        #pragma unroll
        for (int sl = 0; sl < 2; ++sl) {
            int s = s0 + sl * 2;
            float a = b_gs[n] + b_ls[n];
            #pragma unroll
            for (int q = 0; q < 8; ++q) a += part6[(s*8 + q)*GN + n];
            out[(size_t)(b0 + s) * GN + n] = fmaxf(a, 0.f);
        }
    }
}

extern "C" void kernel_launch(void* const* d_in, const int* in_sizes, int n_in,
                              void* d_out, int out_size, void* d_ws, size_t ws_size,
                              hipStream_t stream) {
    const float* out_state = (const float*)d_in[0];
    const float* img       = (const float*)d_in[1];
    const float* W_loc     = (const float*)d_in[2];
    const float* b_loc     = (const float*)d_in[3];
    const float* W_hg      = (const float*)d_in[4];
    const float* b_hg      = (const float*)d_in[5];
    const float* W_hl      = (const float*)d_in[6];
    const float* b_hl      = (const float*)d_in[7];
    const float* W_gs      = (const float*)d_in[8];
    const float* b_gs      = (const float*)d_in[9];
    const float* W_ls      = (const float*)d_in[10];
    const float* b_ls      = (const float*)d_in[11];
    float* out = (float*)d_out;

    hipLaunchKernelGGL(fused_attn, dim3(NB/SPB), dim3(512), 0, stream,
                       out_state, img, W_loc, b_loc, W_hg, b_hg,
                       W_hl, b_hl, W_gs, b_gs, W_ls, b_ls, out);
}

// Round 6
// 17.500 us; speedup vs baseline: 1.1726x; 1.1726x over previous
//
#include <hip/hip_runtime.h>
#include <math.h>

// ---- problem constants ----
#define NB    512   // batch
#define STATE 512
#define IMS   224
#define TSB   768   // 3*16*16
#define HGN   128
#define GN    256
#define WPITCH 65   // 64 + 1 pad

// depth-1 (32->16) antialiased linear weights: taps at j = 2*o-1 + a
__device__ __forceinline__ void d1w(int o, float w[4]) {
    w[0] = 0.125f; w[1] = 0.375f; w[2] = 0.375f; w[3] = 0.125f;
    if (o == 0)  { w[0] = 0.f;      w[1] = 3.f/7.f; w[2] = 3.f/7.f; w[3] = 1.f/7.f; }
    if (o == 15) { w[0] = 1.f/7.f;  w[1] = 3.f/7.f; w[2] = 3.f/7.f; w[3] = 0.f; }
}
// depth-2 (64->16) weights: taps at j = 4*o-2 + a
__device__ __forceinline__ void d2w(int o, float w[8]) {
    const float s = 1.f/32.f;
    w[0]=1*s; w[1]=3*s; w[2]=5*s; w[3]=7*s; w[4]=7*s; w[5]=5*s; w[6]=3*s; w[7]=1*s;
    if (o == 0)  { const float t=1.f/28.f; w[0]=0.f; w[1]=0.f; w[2]=5*t; w[3]=7*t; w[4]=7*t; w[5]=5*t; w[6]=3*t; w[7]=1*t; }
    if (o == 15) { const float t=1.f/28.f; w[0]=1*t; w[1]=3*t; w[2]=5*t; w[3]=7*t; w[4]=7*t; w[5]=5*t; w[6]=0.f; w[7]=0.f; }
}

#define FMA4(acc, sc, w4) \
    acc.x += (sc) * (w4).x; acc.y += (sc) * (w4).y; \
    acc.z += (sc) * (w4).z; acc.w += (sc) * (w4).w;

// Fully fused: loc -> glimpses -> hg -> hl -> g.  2 samples per block, 512 thr.
// W_hg is register-hoisted and streams from L2 CONCURRENTLY with the
// window-gather + glimpse phases (issue order: state, windows, weights ->
// window ds_write waits vmcnt(48), does not drain the weight stream).
__global__ __launch_bounds__(512, 2) void fused_attn(
    const float* __restrict__ out_state,  // [512][512]
    const float* __restrict__ img,        // [512][224][224]
    const float* __restrict__ W_loc, const float* __restrict__ b_loc,
    const float* __restrict__ W_hg,  const float* __restrict__ b_hg,
    const float* __restrict__ W_hl,  const float* __restrict__ b_hl,
    const float* __restrict__ W_gs,  const float* __restrict__ b_gs,
    const float* __restrict__ W_ls,  const float* __restrict__ b_ls,
    float* __restrict__ out)              // [512][256]
{
    __shared__ float win[2][64 * WPITCH];   // 33.3 KB
    __shared__ float gl[2][TSB];            // 6 KB
    __shared__ float s_hg[2][HGN];
    __shared__ float s_hl[2][HGN];
    __shared__ float part4[2][16][HGN];     // 16 KB
    __shared__ float part6[2][8][GN];       // 16 KB
    __shared__ float red[8][2];
    __shared__ float s_loc[2][2];
    __shared__ int   s_li[2][2];

    const int t  = threadIdx.x;
    const int b0 = blockIdx.x * 2;

    // phase-4/6 thread mapping, computed early for prefetch addressing
    const int cg4 = t & 31, q4 = t >> 5;     // 4 cols of 128, 16 k-groups of 48
    const int cg6 = t & 63, q6 = t >> 6;     // 4 cols of 256, 8 j-groups of 16
    const float* wp4 = W_hg + (size_t)(q4 * 48) * HGN + cg4 * 4;
    const float* wgs = W_gs + (size_t)(q6 * 16) * GN + cg6 * 4;
    const float* wls = W_ls + (size_t)(q6 * 16) * GN + cg6 * 4;

    // ---- phase 1: loc = clip(output @ W_loc + b_loc)
    {
        int s = t >> 8, k = t & 255;
        const float* orow = out_state + (size_t)(b0 + s) * STATE;
        float x0 = orow[k], x1 = orow[k + 256];
        float a0 = x0 * W_loc[k*2]     + x1 * W_loc[(k+256)*2];
        float a1 = x0 * W_loc[k*2 + 1] + x1 * W_loc[(k+256)*2 + 1];
        for (int off = 32; off; off >>= 1) {
            a0 += __shfl_down(a0, off);
            a1 += __shfl_down(a1, off);
        }
        if ((t & 63) == 0) { red[t>>6][0] = a0; red[t>>6][1] = a1; }
    }
    __syncthreads();
    if ((t & 255) == 0) {
        int s = t >> 8;
        float l0 = red[4*s][0]+red[4*s+1][0]+red[4*s+2][0]+red[4*s+3][0] + b_loc[0];
        float l1 = red[4*s][1]+red[4*s+1][1]+red[4*s+2][1]+red[4*s+3][1] + b_loc[1];
        l0 = fminf(fmaxf(l0, -1.f), 1.f);
        l1 = fminf(fmaxf(l1, -1.f), 1.f);
        s_loc[s][0] = l0; s_loc[s][1] = l1;
        s_li[s][0] = (int)rintf((l0 + 1.f) * 0.5f * (float)IMS);
        s_li[s][1] = (int)rintf((l1 + 1.f) * 0.5f * (float)IMS);
    }
    __syncthreads();

    // ---- phase 2a: issue the 16 window loads into registers
    float wwin[16];
    #pragma unroll
    for (int i = 0; i < 16; ++i) {
        int idx = t + i * 512;
        int s = idx >> 12, rem = idx & 4095;
        int r = rem >> 6, c = rem & 63;
        int rr = s_li[s][0] - 32 + r, cc = s_li[s][1] - 32 + c;
        float v = 0.f;
        if ((unsigned)rr < (unsigned)IMS && (unsigned)cc < (unsigned)IMS)
            v = img[(size_t)(b0 + s) * IMS * IMS + rr * IMS + cc];
        wwin[i] = v;
    }

    // ---- weight hoist: issue ALL 48 W_hg float4 loads (stream overlaps ph 2b-3)
    float4 wv[48];
    #pragma unroll
    for (int k = 0; k < 48; ++k)
        wv[k] = *(const float4*)(wp4 + (size_t)k * HGN);

    // ---- phase 2b: commit windows to LDS (waits only on the window loads)
    #pragma unroll
    for (int i = 0; i < 16; ++i) {
        int idx = t + i * 512;
        int s = idx >> 12, rem = idx & 4095;
        int r = rem >> 6, c = rem & 63;
        win[s][r * WPITCH + c] = wwin[i];
    }
    __syncthreads();

    // ---- phase 3: 3-depth glimpses -> gl LDS (LDS-only; weight stream in flight)
    {
        int s = t >> 8, p = t & 255, r = p >> 4, c = p & 15;
        const float* w = win[s];
        gl[s][p] = w[(24 + r) * WPITCH + (24 + c)];
        {
            float wr[4], wc[4];
            d1w(r, wr); d1w(c, wc);
            int jr0 = 16 + 2*r - 1, jc0 = 16 + 2*c - 1;
            float acc = 0.f;
            #pragma unroll
            for (int a = 0; a < 4; ++a) {
                float rowsum = 0.f;
                #pragma unroll
                for (int bb = 0; bb < 4; ++bb)
                    rowsum += wc[bb] * w[(jr0 + a) * WPITCH + (jc0 + bb)];
                acc += wr[a] * rowsum;
            }
            gl[s][256 + p] = acc;
        }
        {
            float wr[8], wc[8];
            d2w(r, wr); d2w(c, wc);
            int jr0 = 4*r - 2, jc0 = 4*c - 2;
            float acc = 0.f;
            #pragma unroll
            for (int a = 0; a < 8; ++a) {
                int jr = min(max(jr0 + a, 0), 63);
                float rowsum = 0.f;
                #pragma unroll
                for (int bb = 0; bb < 8; ++bb) {
                    int jc = min(max(jc0 + bb, 0), 63);
                    rowsum += wc[bb] * w[jr * WPITCH + jc];
                }
                acc += wr[a] * rowsum;
            }
            gl[s][512 + p] = acc;
        }
    }
    __syncthreads();

    // ---- phase 4: hg partials = pure FMA from hoisted regs
    float4 ag[16], bg[16];   // phase-6 weights, issued mid-phase-4
    {
        const float* gl0 = gl[0] + q4 * 48;
        const float* gl1 = gl[1] + q4 * 48;
        float4 acc0 = make_float4(0.f,0.f,0.f,0.f);
        float4 acc1 = acc0;
        #pragma unroll
        for (int kk = 0; kk < 8; ++kk) {
            float4 ga = *(const float4*)(gl0 + kk * 4);
            float4 gb = *(const float4*)(gl1 + kk * 4);
            FMA4(acc0, ga.x, wv[kk*4+0]); FMA4(acc1, gb.x, wv[kk*4+0]);
            FMA4(acc0, ga.y, wv[kk*4+1]); FMA4(acc1, gb.y, wv[kk*4+1]);
            FMA4(acc0, ga.z, wv[kk*4+2]); FMA4(acc1, gb.z, wv[kk*4+2]);
            FMA4(acc0, ga.w, wv[kk*4+3]); FMA4(acc1, gb.w, wv[kk*4+3]);
        }
        // issue phase-6 weight loads now (stream under remaining FMAs + phase 5)
        #pragma unroll
        for (int j = 0; j < 16; ++j) {
            ag[j] = *(const float4*)(wgs + (size_t)j * GN);
            bg[j] = *(const float4*)(wls + (size_t)j * GN);
        }
        #pragma unroll
        for (int kk = 8; kk < 12; ++kk) {
            float4 ga = *(const float4*)(gl0 + kk * 4);
            float4 gb = *(const float4*)(gl1 + kk * 4);
            FMA4(acc0, ga.x, wv[kk*4+0]); FMA4(acc1, gb.x, wv[kk*4+0]);
            FMA4(acc0, ga.y, wv[kk*4+1]); FMA4(acc1, gb.y, wv[kk*4+1]);
            FMA4(acc0, ga.z, wv[kk*4+2]); FMA4(acc1, gb.z, wv[kk*4+2]);
            FMA4(acc0, ga.w, wv[kk*4+3]); FMA4(acc1, gb.w, wv[kk*4+3]);
        }
        *(float4*)&part4[0][q4][cg4 * 4] = acc0;
        *(float4*)&part4[1][q4][cg4 * 4] = acc1;
    }
    __syncthreads();

    // ---- phase 5: reduce hg partials (t<256) + hl (t>=256)
    {
        int u = t & 255, s = u >> 7, col = u & 127;
        if (t < 256) {
            float a = b_hg[col];
            #pragma unroll
            for (int q = 0; q < 16; ++q) a += part4[s][q][col];
            s_hg[s][col] = fmaxf(a, 0.f);
        } else {
            float l0 = s_loc[s][0], l1 = s_loc[s][1];
            s_hl[s][col] = fmaxf(l0 * W_hl[col] + l1 * W_hl[HGN + col] + b_hl[col], 0.f);
        }
    }
    __syncthreads();

    // ---- phase 6: g partials from hoisted ag/bg
    {
        float4 acc0 = make_float4(0.f,0.f,0.f,0.f);
        float4 acc1 = acc0;
        #pragma unroll
        for (int jb = 0; jb < 4; ++jb) {
            float4 h0 = *(const float4*)(s_hg[0] + q6 * 16 + jb * 4);
            float4 h1 = *(const float4*)(s_hg[1] + q6 * 16 + jb * 4);
            float4 e0 = *(const float4*)(s_hl[0] + q6 * 16 + jb * 4);
            float4 e1 = *(const float4*)(s_hl[1] + q6 * 16 + jb * 4);
            FMA4(acc0, h0.x, ag[jb*4+0]); FMA4(acc0, e0.x, bg[jb*4+0]);
            FMA4(acc1, h1.x, ag[jb*4+0]); FMA4(acc1, e1.x, bg[jb*4+0]);
            FMA4(acc0, h0.y, ag[jb*4+1]); FMA4(acc0, e0.y, bg[jb*4+1]);
            FMA4(acc1, h1.y, ag[jb*4+1]); FMA4(acc1, e1.y, bg[jb*4+1]);
            FMA4(acc0, h0.z, ag[jb*4+2]); FMA4(acc0, e0.z, bg[jb*4+2]);
            FMA4(acc1, h1.z, ag[jb*4+2]); FMA4(acc1, e1.z, bg[jb*4+2]);
            FMA4(acc0, h0.w, ag[jb*4+3]); FMA4(acc0, e0.w, bg[jb*4+3]);
            FMA4(acc1, h1.w, ag[jb*4+3]); FMA4(acc1, e1.w, bg[jb*4+3]);
        }
        *(float4*)&part6[0][q6][cg6 * 4] = acc0;
        *(float4*)&part6[1][q6][cg6 * 4] = acc1;
    }
    __syncthreads();
    {
        int s = t >> 8, n = t & 255;
        float a = b_gs[n] + b_ls[n];
        #pragma unroll
        for (int q = 0; q < 8; ++q) a += part6[s][q][n];
        out[(size_t)(b0 + s) * GN + n] = fmaxf(a, 0.f);
    }
}

extern "C" void kernel_launch(void* const* d_in, const int* in_sizes, int n_in,
                              void* d_out, int out_size, void* d_ws, size_t ws_size,
                              hipStream_t stream) {
    const float* out_state = (const float*)d_in[0];
    const float* img       = (const float*)d_in[1];
    const float* W_loc     = (const float*)d_in[2];
    const float* b_loc     = (const float*)d_in[3];
    const float* W_hg      = (const float*)d_in[4];
    const float* b_hg      = (const float*)d_in[5];
    const float* W_hl      = (const float*)d_in[6];
    const float* b_hl      = (const float*)d_in[7];
    const float* W_gs      = (const float*)d_in[8];
    const float* b_gs      = (const float*)d_in[9];
    const float* W_ls      = (const float*)d_in[10];
    const float* b_ls      = (const float*)d_in[11];
    float* out = (float*)d_out;

    hipLaunchKernelGGL(fused_attn, dim3(NB/2), dim3(512), 0, stream,
                       out_state, img, W_loc, b_loc, W_hg, b_hg,
                       W_hl, b_hl, W_gs, b_gs, W_ls, b_ls, out);
}